// Round 1
// baseline (718.833 us; speedup 1.0000x reference)
//
#include <hip/hip_runtime.h>
#include <hip/hip_bf16.h>

// ProbSparse attention (Informer). B=4, L=2048, H=8, D=64, S=TOP=40.
// Inputs (f32 unless noted): queries (B,L,H,D), keys (B,L,H,D), values (B,L,H,D),
// attn_mask (1, bool, unused), index_sample (L,S) int32.
// Output: context (B,H,L,D) f32.

constexpr int B = 4, L = 2048, H = 8, D = 64, S = 40, TOP = 40;

// ---------------- Kernel A: sparsity measure M ----------------
// one wave (64 lanes) per (b,h,l) row; 4 rows per 256-thread block
__global__ void compute_M(const float* __restrict__ Q, const float* __restrict__ K,
                          const int* __restrict__ idx, float* __restrict__ M) {
    int r = blockIdx.x * 4 + (threadIdx.x >> 6);   // r in [0, B*H*L)
    int lane = threadIdx.x & 63;
    int b = r >> 14;            // H*L = 16384
    int h = (r >> 11) & 7;
    int l = r & (L - 1);
    float q = Q[(((b * L + l) * H + h) << 6) + lane];
    float maxv = -1e38f, sumv = 0.f;
    for (int s = 0; s < S; ++s) {
        int ki = idx[l * S + s];
        float kv = K[(((b * L + ki) * H + h) << 6) + lane];
        float p = q * kv;
        #pragma unroll
        for (int off = 32; off > 0; off >>= 1) p += __shfl_xor(p, off, 64);
        maxv = fmaxf(maxv, p);
        sumv += p;
    }
    if (lane == 0) M[r] = maxv - sumv * (1.0f / (float)L);
}

// ---------------- Kernel B: top-40 per (b,h) ----------------
__global__ void topk_M(const float* __restrict__ M, int* __restrict__ Mtop) {
    __shared__ float sm[L];
    __shared__ float redV[256];
    __shared__ int   redI[256];
    int bh = blockIdx.x;
    int t = threadIdx.x;
    for (int i = t; i < L; i += 256) sm[i] = M[bh * L + i];
    __syncthreads();
    for (int it = 0; it < TOP; ++it) {
        float bv = -1e38f; int bi = L;
        for (int i = t; i < L; i += 256) {
            float v = sm[i];
            if (v > bv) { bv = v; bi = i; }   // ascending i: ties keep lowest i
        }
        redV[t] = bv; redI[t] = bi;
        __syncthreads();
        for (int off = 128; off > 0; off >>= 1) {
            if (t < off) {
                float v2 = redV[t + off]; int i2 = redI[t + off];
                if (v2 > redV[t] || (v2 == redV[t] && i2 < redI[t])) {
                    redV[t] = v2; redI[t] = i2;
                }
            }
            __syncthreads();
        }
        if (t == 0) { Mtop[bh * TOP + it] = redI[0]; sm[redI[0]] = -1e38f; }
        __syncthreads();
    }
}

// ---------------- Kernel C1: V mean over L per (b,h,d) ----------------
__global__ void vmean(const float* __restrict__ V, float* __restrict__ mean) {
    int bh = blockIdx.x; int b = bh >> 3, h = bh & 7;
    int t = threadIdx.x; int d = t & 63; int c = t >> 6;   // 4 chunks of 512
    float acc = 0.f;
    for (int l = c * 512; l < (c + 1) * 512; ++l)
        acc += V[(((b * L + l) * H + h) << 6) + d];
    __shared__ float red[256];
    red[t] = acc; __syncthreads();
    if (t < 128) red[t] += red[t + 128];
    __syncthreads();
    if (t < 64) mean[bh * 64 + t] = (red[t] + red[t + 64]) * (1.0f / (float)L);
}

// ---------------- Kernel C2: broadcast-fill context with mean ----------------
__global__ void fill_ctx(const float* __restrict__ mean, float4* __restrict__ out) {
    const int N4 = B * H * L * D / 4;                  // 1,048,576
    for (int i = blockIdx.x * 256 + threadIdx.x; i < N4; i += gridDim.x * 256) {
        int bh = i >> 15;                              // L*D/4 = 32768
        int d4 = i & 15;
        out[i] = ((const float4*)mean)[bh * 16 + d4];
    }
}

// ---------------- Kernel D: full attention for selected queries + scatter ----------------
__global__ void sel_attn(const float* __restrict__ Q, const float* __restrict__ K,
                         const float* __restrict__ V, const int* __restrict__ Mtop,
                         float* __restrict__ out) {
    __shared__ float qs[D];
    __shared__ float p[L];
    __shared__ float red[256];
    int blk = blockIdx.x;            // bh*TOP + u
    int bh = blk / TOP, u = blk - bh * TOP;
    int b = bh >> 3, h = bh & 7;
    int t = threadIdx.x;
    int lsel = Mtop[bh * TOP + u];
    if (t < 64) qs[t] = Q[(((b * L + lsel) * H + h) << 6) + t];
    __syncthreads();
    const float scale = 0.125f;      // 1/sqrt(64)
    // scores: thread t handles k = kk*256 + t
    float lmax = -1e38f;
    for (int kk = 0; kk < 8; ++kk) {
        int k = kk * 256 + t;
        const float4* krow = (const float4*)&K[((b * L + k) * H + h) << 6];
        const float4* q4 = (const float4*)qs;
        float acc = 0.f;
        #pragma unroll
        for (int j = 0; j < 16; ++j) {
            float4 kv = krow[j]; float4 qv = q4[j];
            acc += qv.x * kv.x + qv.y * kv.y + qv.z * kv.z + qv.w * kv.w;
        }
        acc *= scale;
        p[k] = acc;
        lmax = fmaxf(lmax, acc);
    }
    red[t] = lmax; __syncthreads();
    for (int off = 128; off > 0; off >>= 1) {
        if (t < off) red[t] = fmaxf(red[t], red[t + off]);
        __syncthreads();
    }
    float gmax = red[0];
    __syncthreads();
    float lsum = 0.f;
    for (int kk = 0; kk < 8; ++kk) {
        int k = kk * 256 + t;
        float e = expf(p[k] - gmax);
        p[k] = e;
        lsum += e;
    }
    red[t] = lsum; __syncthreads();
    for (int off = 128; off > 0; off >>= 1) {
        if (t < off) red[t] += red[t + off];
        __syncthreads();
    }
    float inv = 1.0f / red[0];
    __syncthreads();
    // PV: lane d = t&63, chunk c = t>>6 over 512 k's
    int d = t & 63, c = t >> 6;
    float acc = 0.f;
    for (int k = c * 512; k < (c + 1) * 512; ++k)
        acc += p[k] * V[(((b * L + k) * H + h) << 6) + d];
    red[t] = acc; __syncthreads();
    if (t < 128) red[t] += red[t + 128];
    __syncthreads();
    if (t < 64) out[((bh * L + lsel) << 6) + t] = (red[t] + red[t + 64]) * inv;
}

extern "C" void kernel_launch(void* const* d_in, const int* in_sizes, int n_in,
                              void* d_out, int out_size, void* d_ws, size_t ws_size,
                              hipStream_t stream) {
    const float* Q = (const float*)d_in[0];
    const float* K = (const float*)d_in[1];
    const float* V = (const float*)d_in[2];
    // d_in[3] = attn_mask (unused)
    const int* idx = (const int*)d_in[4];
    float* out = (float*)d_out;

    // workspace layout
    float* M    = (float*)d_ws;                               // B*H*L floats = 256KB
    int*   Mtop = (int*)((char*)d_ws + 262144);               // B*H*TOP ints = 5KB
    float* mean = (float*)((char*)d_ws + 262144 + 8192);      // B*H*D floats = 8KB

    compute_M<<<B * H * L / 4, 256, 0, stream>>>(Q, K, idx, M);
    topk_M<<<B * H, 256, 0, stream>>>(M, Mtop);
    vmean<<<B * H, 256, 0, stream>>>(V, mean);
    fill_ctx<<<2048, 256, 0, stream>>>(mean, (float4*)out);
    sel_attn<<<B * H * TOP, 256, 0, stream>>>(Q, K, V, Mtop, out);
}

// Round 2
// 239.223 us; speedup vs baseline: 3.0049x; 3.0049x over previous
//
#include <hip/hip_runtime.h>
#include <hip/hip_bf16.h>

// ProbSparse attention (Informer). B=4, L=2048, H=8, D=64, S=TOP=40.
constexpr int B = 4, L = 2048, H = 8, D = 64, S = 40, TOP = 40;
constexpr int C = 128, NC = L / C;   // key chunk size / #chunks for split-K

// ---------------- Kernel A: sparsity measure M ----------------
// one wave per (b,h,l) row; 16-lane groups compute float4 dots, 4 samples in flight
__global__ void compute_M(const float* __restrict__ Q, const float* __restrict__ K,
                          const int* __restrict__ idx, float* __restrict__ M) {
    int r = blockIdx.x * 4 + (threadIdx.x >> 6);   // (b,h,l) row id
    int lane = threadIdx.x & 63;
    int sq = lane >> 4, dq = lane & 15;
    int b = r >> 14, h = (r >> 11) & 7, l = r & (L - 1);
    const float4 q4 = *(const float4*)&Q[(((b * L + l) * H + h) << 6) + dq * 4];
    int myidx = (lane < S) ? idx[l * S + lane] : 0;
    float maxv = -3.4e38f, sumv = 0.f;
    #pragma unroll
    for (int i = 0; i < 10; ++i) {
        int ki = __shfl(myidx, i * 4 + sq, 64);
        const float4 kv = *(const float4*)&K[(((b * L + ki) * H + h) << 6) + dq * 4];
        float p = q4.x * kv.x + q4.y * kv.y + q4.z * kv.z + q4.w * kv.w;
        p += __shfl_xor(p, 1); p += __shfl_xor(p, 2);
        p += __shfl_xor(p, 4); p += __shfl_xor(p, 8);
        maxv = fmaxf(maxv, p); sumv += p;
    }
    maxv = fmaxf(maxv, __shfl_xor(maxv, 16));
    maxv = fmaxf(maxv, __shfl_xor(maxv, 32));
    sumv += __shfl_xor(sumv, 16);
    sumv += __shfl_xor(sumv, 32);
    if (lane == 0) M[r] = maxv - sumv * (1.0f / (float)L);
}

// ---------------- Kernel B: top-40 per (b,h), shuffle-based argmax ----------------
__global__ void topk_M(const float* __restrict__ M, int* __restrict__ Mtop) {
    __shared__ float sm[L];
    __shared__ float wv[4];
    __shared__ int   wi[4];
    int bh = blockIdx.x, t = threadIdx.x;
    int wave = t >> 6, lane = t & 63;
    for (int i = t; i < L; i += 256) sm[i] = M[bh * L + i];
    __syncthreads();
    for (int it = 0; it < TOP; ++it) {
        float bv = -3.4e38f; int bi = L;
        #pragma unroll
        for (int j = 0; j < 8; ++j) {
            int i = j * 256 + t; float v = sm[i];
            if (v > bv) { bv = v; bi = i; }   // ascending i keeps lowest index on ties
        }
        #pragma unroll
        for (int m = 1; m < 64; m <<= 1) {
            float v2 = __shfl_xor(bv, m); int i2 = __shfl_xor(bi, m);
            if (v2 > bv || (v2 == bv && i2 < bi)) { bv = v2; bi = i2; }
        }
        if (lane == 0) { wv[wave] = bv; wi[wave] = bi; }
        __syncthreads();
        if (t == 0) {
            float fv = wv[0]; int fi = wi[0];
            #pragma unroll
            for (int w = 1; w < 4; ++w)
                if (wv[w] > fv || (wv[w] == fv && wi[w] < fi)) { fv = wv[w]; fi = wi[w]; }
            Mtop[bh * TOP + it] = fi;
            sm[fi] = -3.4e38f;
        }
        __syncthreads();
    }
}

// ---------------- Kernel C1: V mean over L per (b,h) ----------------
__global__ void vmean(const float* __restrict__ V, float* __restrict__ mean) {
    int bh = blockIdx.x, b = bh >> 3, h = bh & 7;
    int t = threadIdx.x, d4 = t & 15, c = t >> 4;     // 16 chunks of 128 rows
    float4 acc = make_float4(0.f, 0.f, 0.f, 0.f);
    for (int l = c * 128; l < c * 128 + 128; ++l) {
        const float4 v = *(const float4*)&V[(((b * L + l) * H + h) << 6) + d4 * 4];
        acc.x += v.x; acc.y += v.y; acc.z += v.z; acc.w += v.w;
    }
    __shared__ float4 red[256];
    red[t] = acc;
    __syncthreads();
    for (int off = 128; off >= 16; off >>= 1) {
        if (t < off) {
            float4 o = red[t + off];
            red[t].x += o.x; red[t].y += o.y; red[t].z += o.z; red[t].w += o.w;
        }
        __syncthreads();
    }
    if (t < 16) {
        float4 m = red[t];
        m.x *= (1.0f / L); m.y *= (1.0f / L); m.z *= (1.0f / L); m.w *= (1.0f / L);
        ((float4*)mean)[bh * 16 + t] = m;
    }
}

// ---------------- Kernel C2: broadcast-fill context with mean ----------------
__global__ void fill_ctx(const float* __restrict__ mean, float4* __restrict__ out) {
    const int N4 = B * H * L * D / 4;                  // 1,048,576
    for (int i = blockIdx.x * 256 + threadIdx.x; i < N4; i += gridDim.x * 256) {
        int bh = i >> 15;                              // L*D/4 = 32768
        int d4 = i & 15;
        out[i] = ((const float4*)mean)[bh * 16 + d4];
    }
}

// ---------------- Kernel D1: split-K partial attention ----------------
// grid: (bh, kc). Each block: 128-key chunk vs all 40 selected queries.
// Fixed-shift softmax: e = exp(s*0.125 - 16)  (shift-invariant => same softmax).
__global__ __launch_bounds__(256, 2) void sel_attn_part(
        const float* __restrict__ Q, const float* __restrict__ K,
        const float* __restrict__ V, const int* __restrict__ Mtop,
        float* __restrict__ Npart, float* __restrict__ Zpart) {
    __shared__ float KV[128 * 68];          // union: K^T [64][132] then V [128][68]
    __shared__ float Qs[TOP * 64];
    __shared__ float Ps[TOP * 132];
    __shared__ int   mtop_s[TOP];
    const int blk = blockIdx.x;
    const int bh = blk >> 4, kc = blk & (NC - 1);
    const int b = bh >> 3, h = bh & 7;
    const int t = threadIdx.x;
    const int k0 = kc * C;
    if (t < TOP) mtop_s[t] = Mtop[bh * TOP + t];
    // stage K^T: element (d, kk) at KV[d*132 + kk]
    for (int i = t; i < C * 16; i += 256) {
        int kk = i >> 4, d4 = i & 15;
        const float4 kv = *(const float4*)&K[(((b * L + k0 + kk) * H + h) << 6) + d4 * 4];
        KV[(d4 * 4 + 0) * 132 + kk] = kv.x;
        KV[(d4 * 4 + 1) * 132 + kk] = kv.y;
        KV[(d4 * 4 + 2) * 132 + kk] = kv.z;
        KV[(d4 * 4 + 3) * 132 + kk] = kv.w;
    }
    __syncthreads();                         // K^T + mtop_s ready
    // stage selected Q rows
    for (int i = t; i < TOP * 16; i += 256) {
        int u = i >> 4, d4 = i & 15;
        *(float4*)&Qs[u * 64 + d4 * 4] =
            *(const float4*)&Q[(((b * L + mtop_s[u]) * H + h) << 6) + d4 * 4];
    }
    __syncthreads();
    // scores: thread owns 4 keys (k4*4..+3) x 5 queries (ug*5..+4)
    const int k4 = t & 31, ug = t >> 5;
    float4 acc[5];
    #pragma unroll
    for (int j = 0; j < 5; ++j) acc[j] = make_float4(0.f, 0.f, 0.f, 0.f);
    #pragma unroll
    for (int d4 = 0; d4 < 16; ++d4) {
        const float4 kv0 = *(const float4*)&KV[(d4 * 4 + 0) * 132 + k4 * 4];
        const float4 kv1 = *(const float4*)&KV[(d4 * 4 + 1) * 132 + k4 * 4];
        const float4 kv2 = *(const float4*)&KV[(d4 * 4 + 2) * 132 + k4 * 4];
        const float4 kv3 = *(const float4*)&KV[(d4 * 4 + 3) * 132 + k4 * 4];
        #pragma unroll
        for (int j = 0; j < 5; ++j) {
            const float4 q4 = *(const float4*)&Qs[(ug * 5 + j) * 64 + d4 * 4];
            acc[j].x += q4.x * kv0.x + q4.y * kv1.x + q4.z * kv2.x + q4.w * kv3.x;
            acc[j].y += q4.x * kv0.y + q4.y * kv1.y + q4.z * kv2.y + q4.w * kv3.y;
            acc[j].z += q4.x * kv0.z + q4.y * kv1.z + q4.z * kv2.z + q4.w * kv3.z;
            acc[j].w += q4.x * kv0.w + q4.y * kv1.w + q4.z * kv2.w + q4.w * kv3.w;
        }
    }
    // exp (fixed shift), store P, per-query partial Z
    #pragma unroll
    for (int j = 0; j < 5; ++j) {
        const int u = ug * 5 + j;
        float4 e;
        e.x = __expf(acc[j].x * 0.125f - 16.0f);
        e.y = __expf(acc[j].y * 0.125f - 16.0f);
        e.z = __expf(acc[j].z * 0.125f - 16.0f);
        e.w = __expf(acc[j].w * 0.125f - 16.0f);
        *(float4*)&Ps[u * 132 + k4 * 4] = e;
        float z = e.x + e.y + e.z + e.w;
        z += __shfl_xor(z, 1); z += __shfl_xor(z, 2); z += __shfl_xor(z, 4);
        z += __shfl_xor(z, 8); z += __shfl_xor(z, 16);
        if (k4 == 0) Zpart[(bh * TOP + u) * NC + kc] = z;
    }
    __syncthreads();                         // P ready, K^T reads done
    // restage V over K^T space: V[kk][d] at KV[kk*68 + d]
    for (int i = t; i < C * 16; i += 256) {
        int kk = i >> 4, d4 = i & 15;
        *(float4*)&KV[kk * 68 + d4 * 4] =
            *(const float4*)&V[(((b * L + k0 + kk) * H + h) << 6) + d4 * 4];
    }
    __syncthreads();
    // partial PV: thread owns d4 (4 dims) x up to 3 queries (ug2, ug2+16, ug2+32)
    const int d4v = t & 15, ug2 = t >> 4;
    float4 oacc[3];
    #pragma unroll
    for (int jj = 0; jj < 3; ++jj) oacc[jj] = make_float4(0.f, 0.f, 0.f, 0.f);
    for (int kk = 0; kk < C; ++kk) {
        const float4 vv = *(const float4*)&KV[kk * 68 + d4v * 4];
        #pragma unroll
        for (int jj = 0; jj < 3; ++jj) {
            const int u = ug2 + 16 * jj;
            if (u < TOP) {
                const float e = Ps[u * 132 + kk];
                oacc[jj].x += e * vv.x; oacc[jj].y += e * vv.y;
                oacc[jj].z += e * vv.z; oacc[jj].w += e * vv.w;
            }
        }
    }
    #pragma unroll
    for (int jj = 0; jj < 3; ++jj) {
        const int u = ug2 + 16 * jj;
        if (u < TOP)
            *(float4*)&Npart[((bh * TOP + u) * NC + kc) * 64 + d4v * 4] = oacc[jj];
    }
}

// ---------------- Kernel D2: combine partials + scatter ----------------
__global__ void sel_combine(const int* __restrict__ Mtop, const float* __restrict__ Npart,
                            const float* __restrict__ Zpart, float* __restrict__ out) {
    const int blk = blockIdx.x;              // bh*TOP + u
    const int bh = blk / TOP;
    const int t = threadIdx.x;               // 64
    const int lsel = Mtop[blk];
    float z = 0.f;
    #pragma unroll
    for (int c = 0; c < NC; ++c) z += Zpart[blk * NC + c];
    float n = 0.f;
    #pragma unroll
    for (int c = 0; c < NC; ++c) n += Npart[(blk * NC + c) * 64 + t];
    out[((bh * L + lsel) << 6) + t] = n / z;
}

// ---------------- Fallback kernel (small ws): original fused sel_attn ----------------
__global__ void sel_attn(const float* __restrict__ Q, const float* __restrict__ K,
                         const float* __restrict__ V, const int* __restrict__ Mtop,
                         float* __restrict__ out) {
    __shared__ float qs[D];
    __shared__ float p[L];
    __shared__ float red[256];
    int blk = blockIdx.x;
    int bh = blk / TOP, u = blk - bh * TOP;
    int b = bh >> 3, h = bh & 7;
    int t = threadIdx.x;
    int lsel = Mtop[bh * TOP + u];
    if (t < 64) qs[t] = Q[(((b * L + lsel) * H + h) << 6) + t];
    __syncthreads();
    float lmax = -3.4e38f;
    for (int kk = 0; kk < 8; ++kk) {
        int k = kk * 256 + t;
        const float4* krow = (const float4*)&K[((b * L + k) * H + h) << 6];
        const float4* q4 = (const float4*)qs;
        float acc = 0.f;
        #pragma unroll
        for (int j = 0; j < 16; ++j) {
            float4 kv = krow[j]; float4 qv = q4[j];
            acc += qv.x * kv.x + qv.y * kv.y + qv.z * kv.z + qv.w * kv.w;
        }
        acc *= 0.125f;
        p[k] = acc;
        lmax = fmaxf(lmax, acc);
    }
    red[t] = lmax; __syncthreads();
    for (int off = 128; off > 0; off >>= 1) {
        if (t < off) red[t] = fmaxf(red[t], red[t + off]);
        __syncthreads();
    }
    float gmax = red[0];
    __syncthreads();
    float lsum = 0.f;
    for (int kk = 0; kk < 8; ++kk) {
        int k = kk * 256 + t;
        float e = expf(p[k] - gmax);
        p[k] = e;
        lsum += e;
    }
    red[t] = lsum; __syncthreads();
    for (int off = 128; off > 0; off >>= 1) {
        if (t < off) red[t] += red[t + off];
        __syncthreads();
    }
    float inv = 1.0f / red[0];
    __syncthreads();
    int d = t & 63, c = t >> 6;
    float acc = 0.f;
    for (int k = c * 512; k < (c + 1) * 512; ++k)
        acc += p[k] * V[(((b * L + k) * H + h) << 6) + d];
    red[t] = acc; __syncthreads();
    if (t < 128) red[t] += red[t + 128];
    __syncthreads();
    if (t < 64) out[((bh * L + lsel) << 6) + t] = (red[t] + red[t + 64]) * inv;
}

extern "C" void kernel_launch(void* const* d_in, const int* in_sizes, int n_in,
                              void* d_out, int out_size, void* d_ws, size_t ws_size,
                              hipStream_t stream) {
    const float* Q = (const float*)d_in[0];
    const float* K = (const float*)d_in[1];
    const float* V = (const float*)d_in[2];
    const int* idx = (const int*)d_in[4];
    float* out = (float*)d_out;

    // ws layout (bytes): M[0, 262144) Mtop[262144, +8192) mean[270336, +8192)
    //                    Zpart[278528, +81920) Npart[360448, +5242880) -> end 5603328
    float* M    = (float*)d_ws;
    int*   Mtop = (int*)((char*)d_ws + 262144);
    float* mean = (float*)((char*)d_ws + 270336);
    float* Zpart = (float*)((char*)d_ws + 278528);
    float* Npart = (float*)((char*)d_ws + 360448);
    const size_t WS_NEEDED = 5603328;

    compute_M<<<B * H * L / 4, 256, 0, stream>>>(Q, K, idx, M);
    topk_M<<<B * H, 256, 0, stream>>>(M, Mtop);
    vmean<<<B * H, 256, 0, stream>>>(V, mean);
    fill_ctx<<<2048, 256, 0, stream>>>(mean, (float4*)out);
    if (ws_size >= WS_NEEDED) {
        sel_attn_part<<<B * H * NC, 256, 0, stream>>>(Q, K, V, Mtop, Npart, Zpart);
        sel_combine<<<B * H * TOP, 64, 0, stream>>>(Mtop, Npart, Zpart, out);
    } else {
        sel_attn<<<B * H * TOP, 256, 0, stream>>>(Q, K, V, Mtop, out);
    }
}

// Round 4
// 147.101 us; speedup vs baseline: 4.8867x; 1.6263x over previous
//
#include <hip/hip_runtime.h>
#include <hip/hip_bf16.h>

// ProbSparse attention (Informer). B=4, L=2048, H=8, D=64, S=TOP=40.
constexpr int B = 4, L = 2048, H = 8, D = 64, S = 40, TOP = 40;
constexpr int NMB = B * H * L / 4;   // 16384 M-blocks (4 rows each)

// ================= K_A: compute_M (blocks 0..NMB-1) + vmean partials (next 512) ==========
__global__ __launch_bounds__(256) void kA(const float* __restrict__ Q, const float* __restrict__ K,
                                          const float* __restrict__ V, const int* __restrict__ idx,
                                          float* __restrict__ M, float* __restrict__ Vpart) {
    __shared__ float4 red[256];
    const int t = threadIdx.x;
    if (blockIdx.x < NMB) {
        // ---- sparsity measure M: one wave per (b,h,l) row ----
        int r = blockIdx.x * 4 + (t >> 6);
        int lane = t & 63;
        int sq = lane >> 4, dq = lane & 15;
        int b = r >> 14, h = (r >> 11) & 7, l = r & (L - 1);
        const float4 q4 = *(const float4*)&Q[(((b * L + l) * H + h) << 6) + dq * 4];
        int myidx = (lane < S) ? idx[l * S + lane] : 0;
        int ki[10];
        #pragma unroll
        for (int i = 0; i < 10; ++i) ki[i] = __shfl(myidx, i * 4 + sq, 64);
        float4 kv[10];
        #pragma unroll
        for (int i = 0; i < 10; ++i)
            kv[i] = *(const float4*)&K[(((b * L + ki[i]) * H + h) << 6) + dq * 4];
        float maxv = -3.4e38f, sumv = 0.f;
        #pragma unroll
        for (int i = 0; i < 10; ++i) {
            float p = q4.x * kv[i].x + q4.y * kv[i].y + q4.z * kv[i].z + q4.w * kv[i].w;
            p += __shfl_xor(p, 1); p += __shfl_xor(p, 2);
            p += __shfl_xor(p, 4); p += __shfl_xor(p, 8);
            maxv = fmaxf(maxv, p); sumv += p;
        }
        maxv = fmaxf(maxv, __shfl_xor(maxv, 16));
        maxv = fmaxf(maxv, __shfl_xor(maxv, 32));
        sumv += __shfl_xor(sumv, 16);
        sumv += __shfl_xor(sumv, 32);
        if (lane == 0) M[r] = maxv - sumv * (1.0f / (float)L);
    } else {
        // ---- V mean partials: 512 blocks = (bh, 16 chunks of 128 rows) ----
        int blk = blockIdx.x - NMB;
        int bh = blk >> 4, chunk = blk & 15;
        int b = bh >> 3, h = bh & 7;
        int d4 = t & 15, rr = t >> 4;
        int l0 = chunk * 128;
        float4 acc = make_float4(0.f, 0.f, 0.f, 0.f);
        #pragma unroll
        for (int s = 0; s < 8; ++s) {
            int l = l0 + rr + s * 16;
            float4 v = *(const float4*)&V[(((b * L + l) * H + h) << 6) + d4 * 4];
            acc.x += v.x; acc.y += v.y; acc.z += v.z; acc.w += v.w;
        }
        red[t] = acc;
        __syncthreads();
        #pragma unroll
        for (int off = 8; off > 0; off >>= 1) {
            if (rr < off) {
                float4 o = red[t + off * 16];
                red[t].x += o.x; red[t].y += o.y; red[t].z += o.z; red[t].w += o.w;
            }
            __syncthreads();
        }
        if (rr == 0) *(float4*)&Vpart[(bh * 16 + chunk) * 64 + d4 * 4] = red[t];
    }
}

// ================= K_B: register top-40 (one wave per bh, blocks 0..7) + mean finalize (8..15)
__global__ __launch_bounds__(256) void kB(const float* __restrict__ M, const float* __restrict__ Vpart,
                                          int* __restrict__ Mtop, float* __restrict__ mean) {
    const int t = threadIdx.x;
    if (blockIdx.x < 8) {
        int lane = t & 63;
        int bh = blockIdx.x * 4 + (t >> 6);
        float v[32];
        #pragma unroll
        for (int j = 0; j < 32; ++j) v[j] = M[bh * L + j * 64 + lane];
        float bv = v[0]; int bj = 0;
        #pragma unroll
        for (int j = 1; j < 32; ++j) if (v[j] > bv) { bv = v[j]; bj = j; }
        for (int it = 0; it < TOP; ++it) {
            float cv = bv; int ci = bj * 64 + lane;
            #pragma unroll
            for (int m = 1; m < 64; m <<= 1) {
                float ov = __shfl_xor(cv, m); int oi = __shfl_xor(ci, m);
                if (ov > cv || (ov == cv && oi < ci)) { cv = ov; ci = oi; }
            }
            if (lane == 0) Mtop[bh * TOP + it] = ci;
            if (lane == (ci & 63)) {          // winner lane: kill + rescan (static indices)
                int killj = ci >> 6;
                bv = -3.4e38f; bj = 0;
                #pragma unroll
                for (int j = 0; j < 32; ++j) {
                    if (j == killj) v[j] = -3.4e38f;
                    if (v[j] > bv) { bv = v[j]; bj = j; }
                }
            }
        }
    } else {
        int bh = (blockIdx.x - 8) * 4 + (t >> 6);
        int d = t & 63;
        float s = 0.f;
        #pragma unroll
        for (int c = 0; c < 16; ++c) s += Vpart[(bh * 16 + c) * 64 + d];
        mean[bh * 64 + d] = s * (1.0f / (float)L);
    }
}

// ================= K_C: split-K selected attention (blocks [0, B*H*NCC)) + fill (next 2048)
// Fixed-shift softmax: e = exp(s*0.125 - 16), shift-invariant.
template <int CC>
__global__ __launch_bounds__(256) void kC(const float* __restrict__ Q, const float* __restrict__ K,
                                          const float* __restrict__ V, const int* __restrict__ Mtop,
                                          const float* __restrict__ mean, float* __restrict__ Npart,
                                          float* __restrict__ Zpart, float* __restrict__ out) {
    constexpr int NCC = L / CC;
    constexpr int KPT = CC / 32;                       // keys per thread in score phase
    constexpr int LDK = CC + (KPT == 4 ? 4 : 2);       // K^T row stride
    constexpr int LDP = LDK;
    constexpr int LDV = 68;
    constexpr int KVSZ = (CC * LDV > 64 * LDK) ? CC * LDV : 64 * LDK;
    __shared__ float KV[KVSZ];
    __shared__ float Qs[TOP * 64];
    __shared__ float Ps[TOP * LDP];
    __shared__ int mtop_s[TOP];
    const int t = threadIdx.x;
    const int nsel = B * H * NCC;
    if (blockIdx.x >= nsel) {
        // ---- broadcast-fill context with mean ----
        const int N4 = B * H * L * D / 4;
        const float4* m4 = (const float4*)mean;
        float4* o4 = (float4*)out;
        for (int i = (blockIdx.x - nsel) * 256 + t; i < N4; i += 2048 * 256) {
            int bh = i >> 15, d4 = i & 15;
            o4[i] = m4[bh * 16 + d4];
        }
        return;
    }
    const int bh = blockIdx.x / NCC, kc = blockIdx.x % NCC;
    const int b = bh >> 3, h = bh & 7;
    const int k0 = kc * CC;
    if (t < TOP) mtop_s[t] = Mtop[bh * TOP + t];
    // stage K^T: KV[d*LDK + kk]
    for (int i = t; i < CC * 16; i += 256) {
        int kk = i >> 4, d4 = i & 15;
        float4 kv = *(const float4*)&K[(((b * L + k0 + kk) * H + h) << 6) + d4 * 4];
        KV[(d4 * 4 + 0) * LDK + kk] = kv.x;
        KV[(d4 * 4 + 1) * LDK + kk] = kv.y;
        KV[(d4 * 4 + 2) * LDK + kk] = kv.z;
        KV[(d4 * 4 + 3) * LDK + kk] = kv.w;
    }
    __syncthreads();
    for (int i = t; i < TOP * 16; i += 256) {
        int u = i >> 4, d4 = i & 15;
        *(float4*)&Qs[u * 64 + d4 * 4] =
            *(const float4*)&Q[(((b * L + mtop_s[u]) * H + h) << 6) + d4 * 4];
    }
    __syncthreads();
    // scores: thread owns KPT keys (k2*KPT..) x 5 queries (ug*5..)
    const int k2 = t & 31, ug = t >> 5;
    float acc[5][KPT];
    #pragma unroll
    for (int j = 0; j < 5; ++j)
        #pragma unroll
        for (int p = 0; p < KPT; ++p) acc[j][p] = 0.f;
    #pragma unroll
    for (int d4 = 0; d4 < 16; ++d4) {
        float kr[4][KPT];
        #pragma unroll
        for (int rr = 0; rr < 4; ++rr)
            #pragma unroll
            for (int p = 0; p < KPT; ++p)
                kr[rr][p] = KV[(d4 * 4 + rr) * LDK + k2 * KPT + p];
        #pragma unroll
        for (int j = 0; j < 5; ++j) {
            float4 q4 = *(const float4*)&Qs[(ug * 5 + j) * 64 + d4 * 4];
            #pragma unroll
            for (int p = 0; p < KPT; ++p)
                acc[j][p] += q4.x * kr[0][p] + q4.y * kr[1][p] + q4.z * kr[2][p] + q4.w * kr[3][p];
        }
    }
    #pragma unroll
    for (int j = 0; j < 5; ++j) {
        int u = ug * 5 + j;
        float z = 0.f;
        #pragma unroll
        for (int p = 0; p < KPT; ++p) {
            float e = __expf(acc[j][p] * 0.125f - 16.0f);
            Ps[u * LDP + k2 * KPT + p] = e;
            z += e;
        }
        z += __shfl_xor(z, 1); z += __shfl_xor(z, 2); z += __shfl_xor(z, 4);
        z += __shfl_xor(z, 8); z += __shfl_xor(z, 16);
        if (k2 == 0) Zpart[(bh * TOP + u) * NCC + kc] = z;
    }
    __syncthreads();
    // restage V row-major over K^T space
    for (int i = t; i < CC * 16; i += 256) {
        int kk = i >> 4, d4 = i & 15;
        *(float4*)&KV[kk * LDV + d4 * 4] =
            *(const float4*)&V[(((b * L + k0 + kk) * H + h) << 6) + d4 * 4];
    }
    __syncthreads();
    // PV: thread owns d4v (4 dims) x queries {ug2, ug2+16, ug2+32(<40)}
    const int d4v = t & 15, ug2 = t >> 4;
    float4 o0 = make_float4(0,0,0,0), o1 = make_float4(0,0,0,0), o2 = make_float4(0,0,0,0);
    #pragma unroll 4
    for (int kk = 0; kk < CC; ++kk) {
        float4 vv = *(const float4*)&KV[kk * LDV + d4v * 4];
        float e0 = Ps[ug2 * LDP + kk];
        float e1 = Ps[(ug2 + 16) * LDP + kk];
        o0.x += e0 * vv.x; o0.y += e0 * vv.y; o0.z += e0 * vv.z; o0.w += e0 * vv.w;
        o1.x += e1 * vv.x; o1.y += e1 * vv.y; o1.z += e1 * vv.z; o1.w += e1 * vv.w;
        if (ug2 < 8) {                        // wave-uniform branch
            float e2 = Ps[(ug2 + 32) * LDP + kk];
            o2.x += e2 * vv.x; o2.y += e2 * vv.y; o2.z += e2 * vv.z; o2.w += e2 * vv.w;
        }
    }
    *(float4*)&Npart[((bh * TOP + ug2) * NCC + kc) * 64 + d4v * 4] = o0;
    *(float4*)&Npart[((bh * TOP + ug2 + 16) * NCC + kc) * 64 + d4v * 4] = o1;
    if (ug2 < 8)
        *(float4*)&Npart[((bh * TOP + ug2 + 32) * NCC + kc) * 64 + d4v * 4] = o2;
}

// ================= K_D: combine partials + scatter ==================
template <int NCC>
__global__ __launch_bounds__(256) void kD(const int* __restrict__ Mtop, const float* __restrict__ Npart,
                                          const float* __restrict__ Zpart, float* __restrict__ out) {
    const int t = threadIdx.x;
    const int g = blockIdx.x * 4 + (t >> 6);   // (bh,u) flat in [0,1280)
    const int d = t & 63;
    const int bh = g / TOP;
    const int lsel = Mtop[g];
    float z = 0.f;
    #pragma unroll
    for (int c = 0; c < NCC; ++c) z += Zpart[g * NCC + c];
    float n = 0.f;
    #pragma unroll
    for (int c = 0; c < NCC; ++c) n += Npart[(g * NCC + c) * 64 + d];
    out[((bh * L + lsel) << 6) + d] = n / z;
}

// ================= tier-3 fallback (tiny ws): fused per-query attention + fill ==========
__global__ void fill_ctx(const float* __restrict__ mean, float4* __restrict__ out) {
    const int N4 = B * H * L * D / 4;
    for (int i = blockIdx.x * 256 + threadIdx.x; i < N4; i += gridDim.x * 256) {
        int bh = i >> 15, d4 = i & 15;
        out[i] = ((const float4*)mean)[bh * 16 + d4];
    }
}
__global__ void sel_attn(const float* __restrict__ Q, const float* __restrict__ K,
                         const float* __restrict__ V, const int* __restrict__ Mtop,
                         float* __restrict__ out) {
    __shared__ float qs[D];
    __shared__ float p[L];
    __shared__ float red[256];
    int blk = blockIdx.x;
    int bh = blk / TOP, u = blk - bh * TOP;
    int b = bh >> 3, h = bh & 7;
    int t = threadIdx.x;
    int lsel = Mtop[bh * TOP + u];
    if (t < 64) qs[t] = Q[(((b * L + lsel) * H + h) << 6) + t];
    __syncthreads();
    float lsum = 0.f;
    for (int kk = 0; kk < 8; ++kk) {
        int k = kk * 256 + t;
        const float4* krow = (const float4*)&K[((b * L + k) * H + h) << 6];
        const float4* q4 = (const float4*)qs;
        float acc = 0.f;
        #pragma unroll
        for (int j = 0; j < 16; ++j) {
            float4 kv = krow[j]; float4 qv = q4[j];
            acc += qv.x * kv.x + qv.y * kv.y + qv.z * kv.z + qv.w * kv.w;
        }
        float e = __expf(acc * 0.125f - 16.0f);
        p[k] = e;
        lsum += e;
    }
    red[t] = lsum; __syncthreads();
    for (int off = 128; off > 0; off >>= 1) {
        if (t < off) red[t] += red[t + off];
        __syncthreads();
    }
    float inv = 1.0f / red[0];
    __syncthreads();
    int d = t & 63, c = t >> 6;
    float acc = 0.f;
    for (int k = c * 512; k < (c + 1) * 512; ++k)
        acc += p[k] * V[(((b * L + k) * H + h) << 6) + d];
    red[t] = acc; __syncthreads();
    if (t < 128) red[t] += red[t + 128];
    __syncthreads();
    if (t < 64) out[((bh * L + lsel) << 6) + t] = (red[t] + red[t + 64]) * inv;
}

extern "C" void kernel_launch(void* const* d_in, const int* in_sizes, int n_in,
                              void* d_out, int out_size, void* d_ws, size_t ws_size,
                              hipStream_t stream) {
    const float* Q = (const float*)d_in[0];
    const float* K = (const float*)d_in[1];
    const float* V = (const float*)d_in[2];
    const int* idx = (const int*)d_in[4];
    float* out = (float*)d_out;

    // --- ws layout ---
    // phase-1 (kA/kB): M at [0, 262144)
    // phase-2 (kC/kD): Zpart at [0, 163840), Npart at [163840, +npb)  (overlays dead M)
    // persistent:      Mtop / mean / Vpart after max(Npart end, 262144)
    char* ws = (char*)d_ws;
    const size_t NPB1 = (size_t)B * H * TOP * 32 * 64 * 4;   // NCC=32: 10,485,760
    const size_t NPB2 = (size_t)B * H * TOP * 16 * 64 * 4;   // NCC=16:  5,242,880
    auto layout = [&](size_t npb, size_t& persist) {
        size_t e = 163840 + npb;
        persist = (e > 262144 ? e : 262144);
        return persist + 5120 + 8192 + 131072 + 3072;        // Mtop+mean+Vpart (+pad)
    };
    size_t p1, p2, p3;
    size_t need1 = layout(NPB1, p1);
    size_t need2 = layout(NPB2, p2);
    size_t need3 = layout(0, p3);
    int tier = (ws_size >= need1) ? 1 : (ws_size >= need2) ? 2 : (ws_size >= need3) ? 3 : 0;
    size_t persist = (tier == 1) ? p1 : (tier == 2) ? p2 : p3;

    float* M     = (float*)ws;
    float* Zpart = (float*)ws;
    float* Npart = (float*)(ws + 163840);
    int*   Mtop  = (int*)(ws + persist);
    float* mean  = (float*)(ws + persist + 5120);
    float* Vpart = (float*)(ws + persist + 5120 + 8192);

    kA<<<NMB + 512, 256, 0, stream>>>(Q, K, V, idx, M, Vpart);
    kB<<<16, 256, 0, stream>>>(M, Vpart, Mtop, mean);
    if (tier == 1) {
        kC<64><<<B * H * 32 + 2048, 256, 0, stream>>>(Q, K, V, Mtop, mean, Npart, Zpart, out);
        kD<32><<<320, 256, 0, stream>>>(Mtop, Npart, Zpart, out);
    } else if (tier == 2) {
        kC<128><<<B * H * 16 + 2048, 256, 0, stream>>>(Q, K, V, Mtop, mean, Npart, Zpart, out);
        kD<16><<<320, 256, 0, stream>>>(Mtop, Npart, Zpart, out);
    } else {
        fill_ctx<<<2048, 256, 0, stream>>>(mean, (float4*)out);
        sel_attn<<<B * H * TOP, 256, 0, stream>>>(Q, K, V, Mtop, out);
    }
}

// Round 5
// 111.958 us; speedup vs baseline: 6.4206x; 1.3139x over previous
//
#include <hip/hip_runtime.h>
#include <hip/hip_bf16.h>

// ProbSparse attention (Informer). B=4, L=2048, H=8, D=64, S=TOP=40.
constexpr int B = 4, L = 2048, H = 8, D = 64, S = 40, TOP = 40;
constexpr int NMB = B * H * L / 4;   // 16384 M-blocks (4 rows each)

// ================= K_A: compute_M (blocks 0..NMB-1) + vmean partials (next 512) ==========
__global__ __launch_bounds__(256) void kA(const float* __restrict__ Q, const float* __restrict__ K,
                                          const float* __restrict__ V, const int* __restrict__ idx,
                                          float* __restrict__ M, float* __restrict__ Vpart) {
    __shared__ float4 red[256];
    const int t = threadIdx.x;
    if (blockIdx.x < NMB) {
        // ---- sparsity measure M: one wave per (b,h,l) row ----
        int r = blockIdx.x * 4 + (t >> 6);
        int lane = t & 63;
        int sq = lane >> 4, dq = lane & 15;
        int b = r >> 14, h = (r >> 11) & 7, l = r & (L - 1);
        const float4 q4 = *(const float4*)&Q[(((b * L + l) * H + h) << 6) + dq * 4];
        int myidx = (lane < S) ? idx[l * S + lane] : 0;
        int ki[10];
        #pragma unroll
        for (int i = 0; i < 10; ++i) ki[i] = __shfl(myidx, i * 4 + sq, 64);
        float4 kv[10];
        #pragma unroll
        for (int i = 0; i < 10; ++i)
            kv[i] = *(const float4*)&K[(((b * L + ki[i]) * H + h) << 6) + dq * 4];
        float maxv = -3.4e38f, sumv = 0.f;
        #pragma unroll
        for (int i = 0; i < 10; ++i) {
            float p = q4.x * kv[i].x + q4.y * kv[i].y + q4.z * kv[i].z + q4.w * kv[i].w;
            p += __shfl_xor(p, 1); p += __shfl_xor(p, 2);
            p += __shfl_xor(p, 4); p += __shfl_xor(p, 8);
            maxv = fmaxf(maxv, p); sumv += p;
        }
        maxv = fmaxf(maxv, __shfl_xor(maxv, 16));
        maxv = fmaxf(maxv, __shfl_xor(maxv, 32));
        sumv += __shfl_xor(sumv, 16);
        sumv += __shfl_xor(sumv, 32);
        if (lane == 0) M[r] = maxv - sumv * (1.0f / (float)L);
    } else {
        // ---- V mean partials: 512 blocks = (bh, 16 chunks of 128 rows) ----
        int blk = blockIdx.x - NMB;
        int bh = blk >> 4, chunk = blk & 15;
        int b = bh >> 3, h = bh & 7;
        int d4 = t & 15, rr = t >> 4;
        int l0 = chunk * 128;
        float4 acc = make_float4(0.f, 0.f, 0.f, 0.f);
        #pragma unroll
        for (int s = 0; s < 8; ++s) {
            int l = l0 + rr + s * 16;
            float4 v = *(const float4*)&V[(((b * L + l) * H + h) << 6) + d4 * 4];
            acc.x += v.x; acc.y += v.y; acc.z += v.z; acc.w += v.w;
        }
        red[t] = acc;
        __syncthreads();
        #pragma unroll
        for (int off = 8; off > 0; off >>= 1) {
            if (rr < off) {
                float4 o = red[t + off * 16];
                red[t].x += o.x; red[t].y += o.y; red[t].z += o.z; red[t].w += o.w;
            }
            __syncthreads();
        }
        if (rr == 0) *(float4*)&Vpart[(bh * 16 + chunk) * 64 + d4 * 4] = red[t];
    }
}

// ================= K_B: top-40 (blocks 0..31, one per bh, 8 vals/thread in regs)
//                        + mean finalize (blocks 32..39) =============================
__global__ __launch_bounds__(256) void kB(const float* __restrict__ M, const float* __restrict__ Vpart,
                                          int* __restrict__ Mtop, float* __restrict__ mean) {
    const int t = threadIdx.x;
    if (blockIdx.x < 32) {
        const int bh = blockIdx.x;
        const int lane = t & 63, wid = t >> 6;
        float v[8];                               // 8 regs, statically indexed everywhere
        #pragma unroll
        for (int j = 0; j < 8; ++j) v[j] = M[bh * L + j * 256 + t];
        float bv = v[0]; int bj = 0;              // cached per-thread argmax
        #pragma unroll
        for (int j = 1; j < 8; ++j) if (v[j] > bv) { bv = v[j]; bj = j; }
        __shared__ float swv[4];
        __shared__ int   swi[4];
        __shared__ int   winS;
        for (int it = 0; it < TOP; ++it) {
            float cv = bv; int ci = bj * 256 + t;      // global index l = j*256 + t
            #pragma unroll
            for (int m = 1; m < 64; m <<= 1) {
                float ov = __shfl_xor(cv, m); int oi = __shfl_xor(ci, m);
                if (ov > cv || (ov == cv && oi < ci)) { cv = ov; ci = oi; }
            }
            if (lane == 0) { swv[wid] = cv; swi[wid] = ci; }
            __syncthreads();
            if (t == 0) {
                float fv = swv[0]; int fi = swi[0];
                #pragma unroll
                for (int w = 1; w < 4; ++w)
                    if (swv[w] > fv || (swv[w] == fv && swi[w] < fi)) { fv = swv[w]; fi = swi[w]; }
                Mtop[bh * TOP + it] = fi;
                winS = fi;
            }
            __syncthreads();
            const int wl = winS;
            if ((wl & 255) == t) {                 // owner thread: kill + rescan 8 (static)
                if ((wl >> 8) == 0) v[0] = -3.4e38f;
                if ((wl >> 8) == 1) v[1] = -3.4e38f;
                if ((wl >> 8) == 2) v[2] = -3.4e38f;
                if ((wl >> 8) == 3) v[3] = -3.4e38f;
                if ((wl >> 8) == 4) v[4] = -3.4e38f;
                if ((wl >> 8) == 5) v[5] = -3.4e38f;
                if ((wl >> 8) == 6) v[6] = -3.4e38f;
                if ((wl >> 8) == 7) v[7] = -3.4e38f;
                bv = v[0]; bj = 0;
                #pragma unroll
                for (int j = 1; j < 8; ++j) if (v[j] > bv) { bv = v[j]; bj = j; }
            }
        }
    } else {
        int bh = (blockIdx.x - 32) * 4 + (t >> 6);
        int d = t & 63;
        float s = 0.f;
        #pragma unroll
        for (int c = 0; c < 16; ++c) s += Vpart[(bh * 16 + c) * 64 + d];
        mean[bh * 64 + d] = s * (1.0f / (float)L);
    }
}

// ================= K_C: split-K selected attention (blocks [0, B*H*NCC)) + fill (next 2048)
// Fixed-shift softmax: e = exp(s*0.125 - 16), shift-invariant.
template <int CC>
__global__ __launch_bounds__(256, 4) void kC(const float* __restrict__ Q, const float* __restrict__ K,
                                             const float* __restrict__ V, const int* __restrict__ Mtop,
                                             const float* __restrict__ mean, float* __restrict__ Npart,
                                             float* __restrict__ Zpart, float* __restrict__ out) {
    constexpr int NCC = L / CC;
    constexpr int KPT = CC / 32;                       // keys per thread in score phase
    constexpr int LDK = CC + (KPT == 4 ? 4 : 2);       // K^T row stride
    constexpr int LDP = LDK;
    constexpr int LDV = 68;
    constexpr int KVSZ = (CC * LDV > 64 * LDK) ? CC * LDV : 64 * LDK;
    __shared__ float KV[KVSZ];
    __shared__ float Qs[TOP * 64];
    __shared__ float Ps[TOP * LDP];
    const int t = threadIdx.x;
    const int nsel = B * H * NCC;
    if (blockIdx.x >= nsel) {
        // ---- broadcast-fill context with mean ----
        const int N4 = B * H * L * D / 4;
        const float4* m4 = (const float4*)mean;
        float4* o4 = (float4*)out;
        for (int i = (blockIdx.x - nsel) * 256 + t; i < N4; i += 2048 * 256) {
            int bh = i >> 15, d4 = i & 15;
            o4[i] = m4[bh * 16 + d4];
        }
        return;
    }
    const int bh = blockIdx.x / NCC, kc = blockIdx.x % NCC;
    const int b = bh >> 3, h = bh & 7;
    const int k0 = kc * CC;
    // stage K^T and Q together, single barrier
    for (int i = t; i < CC * 16; i += 256) {
        int kk = i >> 4, d4 = i & 15;
        float4 kv = *(const float4*)&K[(((b * L + k0 + kk) * H + h) << 6) + d4 * 4];
        KV[(d4 * 4 + 0) * LDK + kk] = kv.x;
        KV[(d4 * 4 + 1) * LDK + kk] = kv.y;
        KV[(d4 * 4 + 2) * LDK + kk] = kv.z;
        KV[(d4 * 4 + 3) * LDK + kk] = kv.w;
    }
    for (int i = t; i < TOP * 16; i += 256) {
        int u = i >> 4, d4 = i & 15;
        int lsel = Mtop[bh * TOP + u];                 // L2-hot broadcast load
        *(float4*)&Qs[u * 64 + d4 * 4] =
            *(const float4*)&Q[(((b * L + lsel) * H + h) << 6) + d4 * 4];
    }
    __syncthreads();
    // scores: thread owns KPT keys (k2*KPT..) x 5 queries (ug*5..)
    const int k2 = t & 31, ug = t >> 5;
    float acc[5][KPT];
    #pragma unroll
    for (int j = 0; j < 5; ++j)
        #pragma unroll
        for (int p = 0; p < KPT; ++p) acc[j][p] = 0.f;
    #pragma unroll 4
    for (int d4 = 0; d4 < 16; ++d4) {
        float kr[4][KPT];
        #pragma unroll
        for (int rr = 0; rr < 4; ++rr)
            #pragma unroll
            for (int p = 0; p < KPT; ++p)
                kr[rr][p] = KV[(d4 * 4 + rr) * LDK + k2 * KPT + p];
        #pragma unroll
        for (int j = 0; j < 5; ++j) {
            float4 q4 = *(const float4*)&Qs[(ug * 5 + j) * 64 + d4 * 4];
            #pragma unroll
            for (int p = 0; p < KPT; ++p)
                acc[j][p] += q4.x * kr[0][p] + q4.y * kr[1][p] + q4.z * kr[2][p] + q4.w * kr[3][p];
        }
    }
    #pragma unroll
    for (int j = 0; j < 5; ++j) {
        int u = ug * 5 + j;
        float z = 0.f;
        #pragma unroll
        for (int p = 0; p < KPT; ++p) {
            float e = __expf(acc[j][p] * 0.125f - 16.0f);
            Ps[u * LDP + k2 * KPT + p] = e;
            z += e;
        }
        z += __shfl_xor(z, 1); z += __shfl_xor(z, 2); z += __shfl_xor(z, 4);
        z += __shfl_xor(z, 8); z += __shfl_xor(z, 16);
        if (k2 == 0) Zpart[(bh * TOP + u) * NCC + kc] = z;
    }
    __syncthreads();
    // restage V row-major over K^T space
    for (int i = t; i < CC * 16; i += 256) {
        int kk = i >> 4, d4 = i & 15;
        *(float4*)&KV[kk * LDV + d4 * 4] =
            *(const float4*)&V[(((b * L + k0 + kk) * H + h) << 6) + d4 * 4];
    }
    __syncthreads();
    // PV: thread owns d4v (4 dims) x queries {ug2, ug2+16, ug2+32(<40)}
    const int d4v = t & 15, ug2 = t >> 4;
    float4 o0 = make_float4(0,0,0,0), o1 = make_float4(0,0,0,0), o2 = make_float4(0,0,0,0);
    #pragma unroll 4
    for (int kk = 0; kk < CC; ++kk) {
        float4 vv = *(const float4*)&KV[kk * LDV + d4v * 4];
        float e0 = Ps[ug2 * LDP + kk];
        float e1 = Ps[(ug2 + 16) * LDP + kk];
        o0.x += e0 * vv.x; o0.y += e0 * vv.y; o0.z += e0 * vv.z; o0.w += e0 * vv.w;
        o1.x += e1 * vv.x; o1.y += e1 * vv.y; o1.z += e1 * vv.z; o1.w += e1 * vv.w;
        if (ug2 < 8) {                        // wave-uniform branch
            float e2 = Ps[(ug2 + 32) * LDP + kk];
            o2.x += e2 * vv.x; o2.y += e2 * vv.y; o2.z += e2 * vv.z; o2.w += e2 * vv.w;
        }
    }
    *(float4*)&Npart[((bh * TOP + ug2) * NCC + kc) * 64 + d4v * 4] = o0;
    *(float4*)&Npart[((bh * TOP + ug2 + 16) * NCC + kc) * 64 + d4v * 4] = o1;
    if (ug2 < 8)
        *(float4*)&Npart[((bh * TOP + ug2 + 32) * NCC + kc) * 64 + d4v * 4] = o2;
}

// ================= K_D: combine partials + scatter ==================
template <int NCC>
__global__ __launch_bounds__(256) void kD(const int* __restrict__ Mtop, const float* __restrict__ Npart,
                                          const float* __restrict__ Zpart, float* __restrict__ out) {
    const int t = threadIdx.x;
    const int g = blockIdx.x * 4 + (t >> 6);   // (bh,u) flat in [0,1280)
    const int d = t & 63;
    const int bh = g / TOP;
    const int lsel = Mtop[g];
    float z = 0.f;
    #pragma unroll
    for (int c = 0; c < NCC; ++c) z += Zpart[g * NCC + c];
    float n = 0.f;
    #pragma unroll
    for (int c = 0; c < NCC; ++c) n += Npart[(g * NCC + c) * 64 + d];
    out[((bh * L + lsel) << 6) + d] = n / z;
}

// ================= tier-3 fallback (tiny ws): fused per-query attention + fill ==========
__global__ void fill_ctx(const float* __restrict__ mean, float4* __restrict__ out) {
    const int N4 = B * H * L * D / 4;
    for (int i = blockIdx.x * 256 + threadIdx.x; i < N4; i += gridDim.x * 256) {
        int bh = i >> 15, d4 = i & 15;
        out[i] = ((const float4*)mean)[bh * 16 + d4];
    }
}
__global__ void sel_attn(const float* __restrict__ Q, const float* __restrict__ K,
                         const float* __restrict__ V, const int* __restrict__ Mtop,
                         float* __restrict__ out) {
    __shared__ float qs[D];
    __shared__ float p[L];
    __shared__ float red[256];
    int blk = blockIdx.x;
    int bh = blk / TOP, u = blk - bh * TOP;
    int b = bh >> 3, h = bh & 7;
    int t = threadIdx.x;
    int lsel = Mtop[bh * TOP + u];
    if (t < 64) qs[t] = Q[(((b * L + lsel) * H + h) << 6) + t];
    __syncthreads();
    float lsum = 0.f;
    for (int kk = 0; kk < 8; ++kk) {
        int k = kk * 256 + t;
        const float4* krow = (const float4*)&K[((b * L + k) * H + h) << 6];
        const float4* q4 = (const float4*)qs;
        float acc = 0.f;
        #pragma unroll
        for (int j = 0; j < 16; ++j) {
            float4 kv = krow[j]; float4 qv = q4[j];
            acc += qv.x * kv.x + qv.y * kv.y + qv.z * kv.z + qv.w * kv.w;
        }
        float e = __expf(acc * 0.125f - 16.0f);
        p[k] = e;
        lsum += e;
    }
    red[t] = lsum; __syncthreads();
    for (int off = 128; off > 0; off >>= 1) {
        if (t < off) red[t] += red[t + off];
        __syncthreads();
    }
    float inv = 1.0f / red[0];
    __syncthreads();
    int d = t & 63, c = t >> 6;
    float acc = 0.f;
    for (int k = c * 512; k < (c + 1) * 512; ++k)
        acc += p[k] * V[(((b * L + k) * H + h) << 6) + d];
    red[t] = acc; __syncthreads();
    if (t < 128) red[t] += red[t + 128];
    __syncthreads();
    if (t < 64) out[((bh * L + lsel) << 6) + t] = (red[t] + red[t + 64]) * inv;
}

extern "C" void kernel_launch(void* const* d_in, const int* in_sizes, int n_in,
                              void* d_out, int out_size, void* d_ws, size_t ws_size,
                              hipStream_t stream) {
    const float* Q = (const float*)d_in[0];
    const float* K = (const float*)d_in[1];
    const float* V = (const float*)d_in[2];
    const int* idx = (const int*)d_in[4];
    float* out = (float*)d_out;

    // --- ws layout ---
    // phase-1 (kA/kB): M at [0, 262144)
    // phase-2 (kC/kD): Zpart at [0, 163840), Npart at [163840, +npb)  (overlays dead M)
    // persistent:      Mtop / mean / Vpart after max(Npart end, 262144)
    char* ws = (char*)d_ws;
    const size_t NPB1 = (size_t)B * H * TOP * 32 * 64 * 4;   // NCC=32: 10,485,760
    const size_t NPB2 = (size_t)B * H * TOP * 16 * 64 * 4;   // NCC=16:  5,242,880
    auto layout = [&](size_t npb, size_t& persist) {
        size_t e = 163840 + npb;
        persist = (e > 262144 ? e : 262144);
        return persist + 5120 + 8192 + 131072 + 3072;        // Mtop+mean+Vpart (+pad)
    };
    size_t p1, p2, p3;
    size_t need1 = layout(NPB1, p1);
    size_t need2 = layout(NPB2, p2);
    size_t need3 = layout(0, p3);
    int tier = (ws_size >= need1) ? 1 : (ws_size >= need2) ? 2 : (ws_size >= need3) ? 3 : 0;
    size_t persist = (tier == 1) ? p1 : (tier == 2) ? p2 : p3;

    float* M     = (float*)ws;
    float* Zpart = (float*)ws;
    float* Npart = (float*)(ws + 163840);
    int*   Mtop  = (int*)(ws + persist);
    float* mean  = (float*)(ws + persist + 5120);
    float* Vpart = (float*)(ws + persist + 5120 + 8192);

    kA<<<NMB + 512, 256, 0, stream>>>(Q, K, V, idx, M, Vpart);
    kB<<<40, 256, 0, stream>>>(M, Vpart, Mtop, mean);
    if (tier == 1) {
        kC<64><<<B * H * 32 + 2048, 256, 0, stream>>>(Q, K, V, Mtop, mean, Npart, Zpart, out);
        kD<32><<<320, 256, 0, stream>>>(Mtop, Npart, Zpart, out);
    } else if (tier == 2) {
        kC<128><<<B * H * 16 + 2048, 256, 0, stream>>>(Q, K, V, Mtop, mean, Npart, Zpart, out);
        kD<16><<<320, 256, 0, stream>>>(Mtop, Npart, Zpart, out);
    } else {
        fill_ctx<<<2048, 256, 0, stream>>>(mean, (float4*)out);
        sel_attn<<<B * H * TOP, 256, 0, stream>>>(Q, K, V, Mtop, out);
    }
}